// Round 2
// baseline (367.103 us; speedup 1.0000x reference)
//
#include <hip/hip_runtime.h>

// x: (64, 64, 64, 128) fp32. Element strides: b0=524288, i=8192, j=128, c=1.
// out0 = FWHT over axis i, out1 = FWHT over axis j of out0.
//
// LDS-transpose design: each block processes a tile of 64 (transform axis) x
// 256 (free: a pair of the other spatial axis x 128 channels) floats.
//  - phase 1: global->LDS with dwordx4 (1 KiB/wave-instruction, coalesced)
//  - phase 2: each thread FWHT-64s one LDS column in registers
//             (lanes read consecutive floats -> bank-conflict-free)
//  - phase 3: LDS->global with dwordx4
// LDS pitch 260 floats (256 + 4 pad) keeps float4 alignment.

#define PITCH 260

template <int TSTRIDE, int FOUT, int PAIR_MUL>
__global__ __launch_bounds__(256) void fwht64_lds(const float* __restrict__ in,
                                                  float* __restrict__ out) {
    __shared__ float tile[64 * PITCH];
    const int t    = threadIdx.x;
    const int b0   = blockIdx.x >> 5;   // 64 batches
    const int pair = blockIdx.x & 31;   // 32 pairs of the free spatial axis
    const int base = b0 * 524288 + pair * PAIR_MUL;

    // ---- phase 1: global -> LDS (4096 float4s, 16 per thread) ----
#pragma unroll
    for (int k = 0; k < 16; ++k) {
        const int idx = k * 256 + t;      // 0..4095
        const int row = idx >> 6;         // transform-axis index 0..63
        const int f   = (idx & 63) * 4;   // free index 0..252, step 4
        const int fo  = (f >> 7) * FOUT + (f & 127);
        const float4 v = *(const float4*)(in + base + row * TSTRIDE + fo);
        *(float4*)(&tile[row * PITCH + f]) = v;
    }
    __syncthreads();

    // ---- phase 2: thread t transforms column f = t ----
    float v[64];
#pragma unroll
    for (int r = 0; r < 64; ++r) v[r] = tile[r * PITCH + t];

#pragma unroll
    for (int sh = 0; sh < 6; ++sh) {
        const int h = 1 << sh;
#pragma unroll
        for (int s = 0; s < 64; s += 2 * h) {
#pragma unroll
            for (int u = 0; u < h; ++u) {
                const float a = v[s + u];
                const float b = v[s + u + h];
                v[s + u]     = a + b;
                v[s + u + h] = a - b;
            }
        }
    }

#pragma unroll
    for (int r = 0; r < 64; ++r) tile[r * PITCH + t] = v[r];
    __syncthreads();

    // ---- phase 3: LDS -> global ----
#pragma unroll
    for (int k = 0; k < 16; ++k) {
        const int idx = k * 256 + t;
        const int row = idx >> 6;
        const int f   = (idx & 63) * 4;
        const int fo  = (f >> 7) * FOUT + (f & 127);
        *(float4*)(out + base + row * TSTRIDE + fo) =
            *(const float4*)(&tile[row * PITCH + f]);
    }
}

extern "C" void kernel_launch(void* const* d_in, const int* in_sizes, int n_in,
                              void* d_out, int out_size, void* d_ws, size_t ws_size,
                              hipStream_t stream) {
    const float* x = (const float*)d_in[0];
    float* out0 = (float*)d_out;               // trans_im1
    float* out1 = out0 + 64 * 64 * 64 * 128;   // trans_im2

    const int blocks = 64 * 32;  // b0 x free-axis pairs

    // Kernel A: transform axis i (stride 8192); free = (j pair: stride 128, c).
    //   elem = b0*524288 + jt*256 + i*8192 + jj*128 + c  -> FOUT=128, PAIR_MUL=256
    fwht64_lds<8192, 128, 256><<<blocks, 256, 0, stream>>>(x, out0);

    // Kernel B: transform axis j (stride 128); free = (i pair: stride 8192, c).
    //   elem = b0*524288 + it*16384 + ii*8192 + j*128 + c -> FOUT=8192, PAIR_MUL=16384
    fwht64_lds<128, 8192, 16384><<<blocks, 256, 0, stream>>>(out0, out1);
}